// Round 4
// baseline (433.919 us; speedup 1.0000x reference)
//
#include <hip/hip_runtime.h>
#include <hip/hip_bf16.h>

// (B,N,T,F) = (16,512,24,64). Inputs/outputs are FP32 (reference dtype).
#define BB 16
#define NN 512
#define TT 24
#define FF 64
#define OUT_OFF ((size_t)BB*NN*TT*FF)   // 12582912 floats (of | uf concatenated)

#define AIS 136      // Ai/Aj row stride, elems (272B = 17*16B, odd -> uniform bank spread)
#define XTS 72       // Xt/Ut/O/W row stride (144B = 9*16B, odd)
#define XTSZ 4672    // per-matrix region in SH (64*72 + swizzle slack)

typedef __attribute__((ext_vector_type(8))) short v8s;
typedef __attribute__((ext_vector_type(4))) float v4f;

__device__ inline v4f mfma16(v8s a, v8s b, v4f c) {
    return __builtin_amdgcn_mfma_f32_16x16x32_bf16(a, b, c, 0, 0, 0);
}
__device__ inline unsigned short f2bf(float x) {
    union { __hip_bfloat16 h; unsigned short u; } cv; cv.h = __float2bfloat16(x); return cv.u;
}
__device__ inline float bf2f(unsigned short u) {
    union { float f; unsigned int i; } cv; cv.i = ((unsigned int)u) << 16; return cv.f;
}
// 8 fp32 -> hi/lo bf16 (lo = residual after hi rounding; hi+lo ~16 mantissa bits)
__device__ inline void cvt8(float4 a, float4 b, uint4& hi, uint4& lo) {
    float f[8] = {a.x,a.y,a.z,a.w,b.x,b.y,b.z,b.w};
    union { uint4 v; unsigned short s[8]; } H, L;
    #pragma unroll
    for (int k = 0; k < 8; ++k) {
        unsigned short h = f2bf(f[k]);
        H.s[k] = h;
        L.s[k] = f2bf(f[k] - bf2f(h));
    }
    hi = H.v; lo = L.v;
}

__global__ __launch_bounds__(256, 3)
void spag_kernel(const float* __restrict__ ori, const float* __restrict__ unc,
                 const float* __restrict__ emb, const float* __restrict__ W1,
                 float* __restrict__ out)
{
    // LDS: 17408 + 17408 + 18688 = 53504 B -> 3 blocks/CU (160 KiB LDS)
    __shared__ __align__(16) unsigned short AiH[64*AIS];   // hi of [x_i | emb_i], K=128
    __shared__ __align__(16) unsigned short AiL[64*AIS];   // lo of [x_i | emb_i]
    __shared__ __align__(16) unsigned short SH [2*XTSZ];   // AjH -> AjL -> (Xt|Ut) -> (Ox|Ou)

    const int tid  = threadIdx.x;
    const int bt   = blockIdx.x >> 3;      // 0..383
    const int it   = blockIdx.x & 7;
    const int b    = bt / TT, t = bt % TT;
    const int i0   = it * 64;

    const int lane = tid & 63;
    const int w    = tid >> 6;             // wave -> i rows w*16..w*16+15
    const int q    = lane >> 4;            // quad
    const int lc   = lane & 15;

    const int sr   = tid >> 2;             // staging row 0..63
    const int fcq  = tid & 3;
    const int fc   = fcq * 16;             // staging f-chunk

    // ---- stage Ai hi+lo (once) ----
    {
        const float* xb = ori + ((size_t)((b*NN + i0 + sr)*TT + t))*FF + fc;
        const float* eb = emb + (size_t)(i0 + sr)*FF + fc;
        #pragma unroll
        for (int h = 0; h < 2; ++h) {
            uint4 hi, lo;
            cvt8(((const float4*)xb)[2*h], ((const float4*)xb)[2*h+1], hi, lo);
            *(uint4*)&AiH[sr*AIS + fc + h*8] = hi;
            *(uint4*)&AiL[sr*AIS + fc + h*8] = lo;
            cvt8(((const float4*)eb)[2*h], ((const float4*)eb)[2*h+1], hi, lo);
            *(uint4*)&AiH[sr*AIS + 64 + fc + h*8] = hi;
            *(uint4*)&AiL[sr*AIS + 64 + fc + h*8] = lo;
        }
    }
    __syncthreads();

    // B-operand fragments (i side), held in registers for the whole kernel
    v8s bH[4], bL[4];
    #pragma unroll
    for (int kk = 0; kk < 4; ++kk) {
        bH[kk] = *(const v8s*)&AiH[(w*16+lc)*AIS + kk*32 + q*8];
        bL[kk] = *(const v8s*)&AiL[(w*16+lc)*AIS + kk*32 + q*8];
    }

    v4f accX[4], accU[4];
    #pragma unroll
    for (int ft = 0; ft < 4; ++ft) { accX[ft] = (v4f)(0.0f); accU[ft] = (v4f)(0.0f); }
    float rs    = 0.0f;   // partial softmax denominator for row i = w*16+lc (at current m_run)
    float m_run = 0.0f;   // running row max of relu'd scores (>= 0 always)

    for (int jt = 0; jt < 8; ++jt) {
        const int j0 = jt * 64;
        const size_t jbase = ((size_t)((b*NN + j0 + sr)*TT + t))*FF + fc;
        __syncthreads();                       // SH free (prev PV readers done)

        // ---- stage AjH = hi of [x_j | emb_j] ----
        {
            const float* xb = ori + jbase;
            const float* eb = emb + (size_t)(j0 + sr)*FF + fc;
            #pragma unroll
            for (int h = 0; h < 2; ++h) {
                uint4 hi, lo;
                cvt8(((const float4*)xb)[2*h], ((const float4*)xb)[2*h+1], hi, lo);
                *(uint4*)&SH[sr*AIS + fc + h*8] = hi;
                cvt8(((const float4*)eb)[2*h], ((const float4*)eb)[2*h+1], hi, lo);
                *(uint4*)&SH[sr*AIS + 64 + fc + h*8] = hi;
            }
        }
        __syncthreads();

        // ---- scores pass 1+2: C += AjH.AiH^T + AjH.AiL^T  (S^T: D[j][i], i=lane&15) ----
        v4f C[4] = {(v4f)(0.0f),(v4f)(0.0f),(v4f)(0.0f),(v4f)(0.0f)};
        #pragma unroll
        for (int kk = 0; kk < 4; ++kk) {
            #pragma unroll
            for (int st = 0; st < 4; ++st) {
                v8s a = *(const v8s*)&SH[(st*16+lc)*AIS + kk*32 + q*8];
                C[st] = mfma16(a, bH[kk], C[st]);
                C[st] = mfma16(a, bL[kk], C[st]);
            }
        }
        __syncthreads();                       // AjH reads done

        // ---- stage AjL = lo of [x_j | emb_j] ----
        {
            const float* xb = ori + jbase;
            const float* eb = emb + (size_t)(j0 + sr)*FF + fc;
            #pragma unroll
            for (int h = 0; h < 2; ++h) {
                uint4 hi, lo;
                cvt8(((const float4*)xb)[2*h], ((const float4*)xb)[2*h+1], hi, lo);
                *(uint4*)&SH[sr*AIS + fc + h*8] = lo;
                cvt8(((const float4*)eb)[2*h], ((const float4*)eb)[2*h+1], hi, lo);
                *(uint4*)&SH[sr*AIS + 64 + fc + h*8] = lo;
            }
        }
        __syncthreads();

        // ---- scores pass 3: C += AjL.AiH^T ----
        #pragma unroll
        for (int kk = 0; kk < 4; ++kk) {
            #pragma unroll
            for (int st = 0; st < 4; ++st) {
                v8s a = *(const v8s*)&SH[(st*16+lc)*AIS + kk*32 + q*8];
                C[st] = mfma16(a, bH[kk], C[st]);
            }
        }
        __syncthreads();                       // AjL reads done

        // ---- stage Xt/Ut = x^T,u^T (hi only), swizzled: elem (f,j) at f*XTS+(f>>4)*16+j ----
        {
            const float* xb = ori + jbase;
            const float* ub = unc + jbase;
            float4 xv[4], uv[4];
            #pragma unroll
            for (int h = 0; h < 4; ++h) { xv[h] = ((const float4*)xb)[h]; uv[h] = ((const float4*)ub)[h]; }
            const float* xs = (const float*)xv;
            const float* us = (const float*)uv;
            #pragma unroll
            for (int k = 0; k < 16; ++k) {
                int f = fc + k;
                int off = f*XTS + fcq*16 + sr;
                SH[off]        = f2bf(xs[k]);
                SH[XTSZ + off] = f2bf(us[k]);
            }
        }

        // ---- online softmax: relu, tile row-max, rescale, p = exp(s - m) ----
        float mt = 0.0f;
        #pragma unroll
        for (int st = 0; st < 4; ++st) {
            #pragma unroll
            for (int r = 0; r < 4; ++r) {
                float s = fmaxf(C[st][r], 0.0f);   // relu
                C[st][r] = s;
                mt = fmaxf(mt, s);
            }
        }
        mt = fmaxf(mt, __shfl_xor(mt, 16));
        mt = fmaxf(mt, __shfl_xor(mt, 32));        // row max over this 64-j tile, all quads agree
        float m_new = fmaxf(m_run, mt);
        float alpha = __expf(m_run - m_new);       // <= 1
        rs *= alpha;
        m_run = m_new;
        float alphar[4];
        #pragma unroll
        for (int r = 0; r < 4; ++r) alphar[r] = __shfl(alpha, q*4 + r);  // for acc rows i=w16+q*4+r
        #pragma unroll
        for (int ft = 0; ft < 4; ++ft) {
            #pragma unroll
            for (int r = 0; r < 4; ++r) { accX[ft][r] *= alphar[r]; accU[ft][r] *= alphar[r]; }
        }
        #pragma unroll
        for (int st = 0; st < 4; ++st) {
            #pragma unroll
            for (int r = 0; r < 4; ++r) C[st][r] = __expf(C[st][r] - m_new);  // p in (0,1]
        }

        // ---- repack p: C-layout -> A-layout (in-wave shfl), accumulate rowsum ----
        v8s P[2];
        #pragma unroll
        for (int kk = 0; kk < 2; ++kk) {
            union { v8s v; unsigned short s[8]; } pf;
            #pragma unroll
            for (int jj = 0; jj < 8; ++jj) {
                int src = ((q & 1)*2 + (jj >> 2))*16 + lc;   // lane holding p(i=w16+lc, j)
                float v0 = __shfl(C[2*kk + 0][jj & 3], src);
                float v1 = __shfl(C[2*kk + 1][jj & 3], src);
                float pv = (q >> 1) ? v1 : v0;
                unsigned short pb = f2bf(pv);
                pf.s[jj] = pb;
                rs += bf2f(pb);                  // sum the bf16-rounded value actually used
            }
            P[kk] = pf.v;
        }
        __syncthreads();                       // Xt/Ut ready

        // ---- PV: accX += P . x^T, accU += P . u^T ----
        #pragma unroll
        for (int ft = 0; ft < 4; ++ft) {
            #pragma unroll
            for (int kk = 0; kk < 2; ++kk) {
                v8s bx = *(const v8s*)&SH[(ft*16+lc)*XTS + ft*16 + kk*32 + q*8];
                v8s bu = *(const v8s*)&SH[XTSZ + (ft*16+lc)*XTS + ft*16 + kk*32 + q*8];
                accX[ft] = mfma16(P[kk], bx, accX[ft]);
                accU[ft] = mfma16(P[kk], bu, accU[ft]);
            }
        }
    }

    // ---- epilogue: normalize, O.W1^T, relu, fp32 stores ----
    __syncthreads();                           // all PV reads of SH done
    rs += __shfl_xor(rs, 16);
    rs += __shfl_xor(rs, 32);                  // full row sum for i = w*16+lc (>= 1)
    float inv = 1.0f / rs;
    float invr[4];
    #pragma unroll
    for (int r = 0; r < 4; ++r) invr[r] = __shfl(inv, q*4 + r);  // for i = w*16+q*4+r

    unsigned short* Ox = SH;
    unsigned short* Ou = SH + XTSZ;
    #pragma unroll
    for (int ft = 0; ft < 4; ++ft) {
        #pragma unroll
        for (int r = 0; r < 4; ++r) {
            int row = w*16 + q*4 + r;
            Ox[row*XTS + ft*16 + lc] = f2bf(accX[ft][r] * invr[r]);
            Ou[row*XTS + ft*16 + lc] = f2bf(accU[ft][r] * invr[r]);
        }
    }
    // W1 rows -> AiH region (stride XTS)
    {
        const float* wb = W1 + sr*FF + fc;
        #pragma unroll
        for (int h = 0; h < 2; ++h) {
            uint4 hi, lo;
            cvt8(((const float4*)wb)[2*h], ((const float4*)wb)[2*h+1], hi, lo);
            *(uint4*)&AiH[sr*XTS + fc + h*8] = hi;
        }
    }
    __syncthreads();

    #pragma unroll
    for (int ot = 0; ot < 4; ++ot) {
        v4f ax = (v4f)(0.0f), au = (v4f)(0.0f);
        #pragma unroll
        for (int kk = 0; kk < 2; ++kk) {
            v8s aox = *(const v8s*)&Ox[(w*16+lc)*XTS + kk*32 + q*8];
            v8s aou = *(const v8s*)&Ou[(w*16+lc)*XTS + kk*32 + q*8];
            v8s bw  = *(const v8s*)&AiH[(ot*16+lc)*XTS + kk*32 + q*8];
            ax = mfma16(aox, bw, ax);
            au = mfma16(aou, bw, au);
        }
        #pragma unroll
        for (int r = 0; r < 4; ++r) {
            int i = i0 + w*16 + q*4 + r;
            int o = ot*16 + lc;
            size_t idx = ((size_t)((b*NN + i)*TT + t))*FF + o;
            out[idx]           = fmaxf(ax[r], 0.0f);
            out[OUT_OFF + idx] = fmaxf(au[r], 0.0f);
        }
    }
}

extern "C" void kernel_launch(void* const* d_in, const int* in_sizes, int n_in,
                              void* d_out, int out_size, void* d_ws, size_t ws_size,
                              hipStream_t stream) {
    const float* ori = (const float*)d_in[0];
    const float* unc = (const float*)d_in[1];
    const float* emb = (const float*)d_in[2];
    const float* W1  = (const float*)d_in[3];
    float* out = (float*)d_out;

    spag_kernel<<<dim3(BB*TT*8), dim3(256), 0, stream>>>(ori, unc, emb, W1, out);
}

// Round 5
// 328.206 us; speedup vs baseline: 1.3221x; 1.3221x over previous
//
#include <hip/hip_runtime.h>
#include <hip/hip_bf16.h>

// (B,N,T,F) = (16,512,24,64). FP32 in/out.
#define BB 16
#define NN 512
#define TT 24
#define FF 64
#define OUT_OFF ((size_t)BB*NN*TT*FF)   // 12582912 floats (of | uf concatenated)

#define AIS 136      // Aj row stride, shorts (272B = 17*16B, odd 16B units)
#define XTS 72       // Xt/Ut/O/W row stride (144B = 9*16B, odd)
#define XTSZ 4672    // per-matrix region (64*72 + swizzle slack)

typedef __attribute__((ext_vector_type(8))) short v8s;
typedef __attribute__((ext_vector_type(4))) float v4f;

union U16x8 { uint4 v; unsigned short s[8]; };

__device__ inline v4f mfma16(v8s a, v8s b, v4f c) {
    return __builtin_amdgcn_mfma_f32_16x16x32_bf16(a, b, c, 0, 0, 0);
}
__device__ inline unsigned short f2bf(float x) {
    union { __hip_bfloat16 h; unsigned short u; } cv; cv.h = __float2bfloat16(x); return cv.u;
}
__device__ inline float bf2f(unsigned short u) {
    union { float f; unsigned int i; } cv; cv.i = ((unsigned int)u) << 16; return cv.f;
}
__device__ inline void cvt8u(const float* f, U16x8& H, U16x8& L) {
    #pragma unroll
    for (int k = 0; k < 8; ++k) {
        unsigned short h = f2bf(f[k]);
        H.s[k] = h;
        L.s[k] = f2bf(f[k] - bf2f(h));
    }
}

__global__ __launch_bounds__(256, 3)
void spag_kernel(const float* __restrict__ ori, const float* __restrict__ unc,
                 const float* __restrict__ emb, const float* __restrict__ W1,
                 float* __restrict__ out)
{
    // One 53504B arena, 3 blocks/CU (160 KiB LDS). Regions:
    //   AjH[64*AIS] | AjL[64*AIS] | XT[XTSZ] | UT[XTSZ]
    // Prologue aliases AjH/AjL as Ai hi/lo staging; epilogue aliases
    // XT/UT as Ox/Ou and AjH as the W1 tile.
    __shared__ __align__(16) unsigned short SH[2*64*AIS + 2*XTSZ];
    unsigned short* AjH = SH;
    unsigned short* AjL = SH + 64*AIS;
    unsigned short* XT  = SH + 2*64*AIS;
    unsigned short* UT  = XT + XTSZ;

    const int tid  = threadIdx.x;
    const int bt   = blockIdx.x >> 3;      // 0..383
    const int it   = blockIdx.x & 7;
    const int b    = bt / TT, t = bt % TT;
    const int i0   = it * 64;

    const int lane = tid & 63;
    const int w    = tid >> 6;             // wave -> i rows w*16..w*16+15
    const int q    = lane >> 4;            // quad
    const int lc   = lane & 15;

    // ---- prologue: stage Ai hi/lo (into AjH/AjL regions), load B-frags ----
    {
        const int sr = tid >> 2, fc = (tid & 3) * 16;
        const float* xb = ori + ((size_t)((b*NN + i0 + sr)*TT + t))*FF + fc;
        const float* eb = emb + (size_t)(i0 + sr)*FF + fc;
        float tf[8]; U16x8 H, L;
        #pragma unroll
        for (int h = 0; h < 2; ++h) {
            *(float4*)&tf[0] = ((const float4*)xb)[2*h];
            *(float4*)&tf[4] = ((const float4*)xb)[2*h+1];
            cvt8u(tf, H, L);
            *(uint4*)&AjH[sr*AIS + fc + h*8] = H.v;
            *(uint4*)&AjL[sr*AIS + fc + h*8] = L.v;
            *(float4*)&tf[0] = ((const float4*)eb)[2*h];
            *(float4*)&tf[4] = ((const float4*)eb)[2*h+1];
            cvt8u(tf, H, L);
            *(uint4*)&AjH[sr*AIS + 64 + fc + h*8] = H.v;
            *(uint4*)&AjL[sr*AIS + 64 + fc + h*8] = L.v;
        }
    }
    __syncthreads();

    v8s bH[4], bL[4];   // i-side fragments, register-resident all kernel
    #pragma unroll
    for (int kk = 0; kk < 4; ++kk) {
        bH[kk] = *(const v8s*)&AjH[(w*16+lc)*AIS + kk*32 + q*8];
        bL[kk] = *(const v8s*)&AjL[(w*16+lc)*AIS + kk*32 + q*8];
    }

    v4f accX[4], accU[4];
    #pragma unroll
    for (int ft = 0; ft < 4; ++ft) { accX[ft] = (v4f)(0.0f); accU[ft] = (v4f)(0.0f); }
    float rs    = 0.0f;   // softmax denom partial for row i = w*16+lc (at m_run)
    float m_run = 0.0f;   // running row max of relu'd scores (>= 0)

    for (int jt = 0; jt < 8; ++jt) {
        const int j0 = jt * 64;
        __syncthreads();   // prev iter's LDS readers done (and prologue frag reads, jt=0)

        // ---- single-pass staging: AjH, AjL, XT, UT ----
        {
            const int pj = tid >> 3;           // j pair (2pj, 2pj+1)
            const int f0 = (tid & 7) * 8;      // f chunk
            const int j  = 2 * pj;
            const size_t r0 = ((size_t)((b*NN + j0 + j)*TT + t))*FF + f0;
            const size_t r1 = r0 + (size_t)TT*FF;
            float t0[8], t1[8]; U16x8 H0, L0, H1, L1;

            // ori: hi->AjH, lo->AjL, hi also transposed -> XT
            *(float4*)&t0[0] = *(const float4*)(ori + r0);
            *(float4*)&t0[4] = *(const float4*)(ori + r0 + 4);
            *(float4*)&t1[0] = *(const float4*)(ori + r1);
            *(float4*)&t1[4] = *(const float4*)(ori + r1 + 4);
            cvt8u(t0, H0, L0); cvt8u(t1, H1, L1);
            *(uint4*)&AjH[ j   *AIS + f0] = H0.v;
            *(uint4*)&AjH[(j+1)*AIS + f0] = H1.v;
            *(uint4*)&AjL[ j   *AIS + f0] = L0.v;
            *(uint4*)&AjL[(j+1)*AIS + f0] = L1.v;
            #pragma unroll
            for (int k = 0; k < 8; ++k) {
                int f = f0 + k;
                int off = f*XTS + (f>>4)*16 + j;
                *(unsigned int*)&XT[off] =
                    (unsigned int)H0.s[k] | ((unsigned int)H1.s[k] << 16);
            }
            // emb: hi->AjH(+64), lo->AjL(+64)
            const float* e0 = emb + (size_t)(j0 + j)*FF + f0;
            *(float4*)&t0[0] = *(const float4*)(e0);
            *(float4*)&t0[4] = *(const float4*)(e0 + 4);
            *(float4*)&t1[0] = *(const float4*)(e0 + FF);
            *(float4*)&t1[4] = *(const float4*)(e0 + FF + 4);
            cvt8u(t0, H0, L0); cvt8u(t1, H1, L1);
            *(uint4*)&AjH[ j   *AIS + 64 + f0] = H0.v;
            *(uint4*)&AjH[(j+1)*AIS + 64 + f0] = H1.v;
            *(uint4*)&AjL[ j   *AIS + 64 + f0] = L0.v;
            *(uint4*)&AjL[(j+1)*AIS + 64 + f0] = L1.v;
            // unc: hi only, transposed -> UT
            *(float4*)&t0[0] = *(const float4*)(unc + r0);
            *(float4*)&t0[4] = *(const float4*)(unc + r0 + 4);
            *(float4*)&t1[0] = *(const float4*)(unc + r1);
            *(float4*)&t1[4] = *(const float4*)(unc + r1 + 4);
            #pragma unroll
            for (int k = 0; k < 8; ++k) {
                int f = f0 + k;
                int off = f*XTS + (f>>4)*16 + j;
                *(unsigned int*)&UT[off] =
                    (unsigned int)f2bf(t0[k]) | ((unsigned int)f2bf(t1[k]) << 16);
            }
        }
        __syncthreads();

        // ---- scores: C(S^T)[j][i] = Aj . Ai^T, hi/lo split (48 MFMA) ----
        v4f C[4] = {(v4f)(0.0f),(v4f)(0.0f),(v4f)(0.0f),(v4f)(0.0f)};
        #pragma unroll
        for (int kk = 0; kk < 4; ++kk) {
            #pragma unroll
            for (int st = 0; st < 4; ++st) {
                v8s aH = *(const v8s*)&AjH[(st*16+lc)*AIS + kk*32 + q*8];
                v8s aL = *(const v8s*)&AjL[(st*16+lc)*AIS + kk*32 + q*8];
                C[st] = mfma16(aH, bH[kk], C[st]);
                C[st] = mfma16(aH, bL[kk], C[st]);
                C[st] = mfma16(aL, bH[kk], C[st]);
            }
        }

        // ---- online softmax: relu, tile row-max, rescale, p = exp(s - m) ----
        float mt = 0.0f;
        #pragma unroll
        for (int st = 0; st < 4; ++st) {
            #pragma unroll
            for (int r = 0; r < 4; ++r) {
                float s = fmaxf(C[st][r], 0.0f);
                C[st][r] = s;
                mt = fmaxf(mt, s);
            }
        }
        mt = fmaxf(mt, __shfl_xor(mt, 16));
        mt = fmaxf(mt, __shfl_xor(mt, 32));
        float m_new = fmaxf(m_run, mt);
        float alpha = __expf(m_run - m_new);
        rs *= alpha;
        m_run = m_new;
        float alphar[4];
        #pragma unroll
        for (int r = 0; r < 4; ++r) alphar[r] = __shfl(alpha, q*4 + r);
        #pragma unroll
        for (int ft = 0; ft < 4; ++ft) {
            #pragma unroll
            for (int r = 0; r < 4; ++r) { accX[ft][r] *= alphar[r]; accU[ft][r] *= alphar[r]; }
        }
        #pragma unroll
        for (int st = 0; st < 4; ++st) {
            #pragma unroll
            for (int r = 0; r < 4; ++r) C[st][r] = __expf(C[st][r] - m_new);
        }

        // ---- repack p: C-layout -> A-layout (in-wave shfl), accumulate rowsum ----
        v8s P[2];
        #pragma unroll
        for (int kk = 0; kk < 2; ++kk) {
            union { v8s v; unsigned short s[8]; } pf;
            #pragma unroll
            for (int jj = 0; jj < 8; ++jj) {
                int src = ((q & 1)*2 + (jj >> 2))*16 + lc;
                float v0 = __shfl(C[2*kk + 0][jj & 3], src);
                float v1 = __shfl(C[2*kk + 1][jj & 3], src);
                float pv = (q >> 1) ? v1 : v0;
                unsigned short pb = f2bf(pv);
                pf.s[jj] = pb;
                rs += bf2f(pb);
            }
            P[kk] = pf.v;
        }

        // ---- PV: accX += P . x^T, accU += P . u^T (16 MFMA) ----
        #pragma unroll
        for (int ft = 0; ft < 4; ++ft) {
            #pragma unroll
            for (int kk = 0; kk < 2; ++kk) {
                v8s bx = *(const v8s*)&XT[(ft*16+lc)*XTS + ft*16 + kk*32 + q*8];
                v8s bu = *(const v8s*)&UT[(ft*16+lc)*XTS + ft*16 + kk*32 + q*8];
                accX[ft] = mfma16(P[kk], bx, accX[ft]);
                accU[ft] = mfma16(P[kk], bu, accU[ft]);
            }
        }
    }

    // ---- epilogue: normalize, O.W1^T, relu, fp32 stores ----
    __syncthreads();                           // all PV reads done
    rs += __shfl_xor(rs, 16);
    rs += __shfl_xor(rs, 32);                  // full row sum (>= 1)
    float inv = 1.0f / rs;
    float invr[4];
    #pragma unroll
    for (int r = 0; r < 4; ++r) invr[r] = __shfl(inv, q*4 + r);

    unsigned short* Ox = XT;
    unsigned short* Ou = UT;
    #pragma unroll
    for (int ft = 0; ft < 4; ++ft) {
        #pragma unroll
        for (int r = 0; r < 4; ++r) {
            int row = w*16 + q*4 + r;
            Ox[row*XTS + ft*16 + lc] = f2bf(accX[ft][r] * invr[r]);
            Ou[row*XTS + ft*16 + lc] = f2bf(accU[ft][r] * invr[r]);
        }
    }
    // W1 tile -> AjH region (stride XTS)
    {
        const int sr = tid >> 2, fc = (tid & 3) * 16;
        const float* wb = W1 + sr*FF + fc;
        float tf[8]; U16x8 H, L;
        #pragma unroll
        for (int h = 0; h < 2; ++h) {
            *(float4*)&tf[0] = ((const float4*)wb)[2*h];
            *(float4*)&tf[4] = ((const float4*)wb)[2*h+1];
            cvt8u(tf, H, L);
            *(uint4*)&AjH[sr*XTS + fc + h*8] = H.v;
        }
    }
    __syncthreads();

    #pragma unroll
    for (int ot = 0; ot < 4; ++ot) {
        v4f ax = (v4f)(0.0f), au = (v4f)(0.0f);
        #pragma unroll
        for (int kk = 0; kk < 2; ++kk) {
            v8s aox = *(const v8s*)&Ox[(w*16+lc)*XTS + kk*32 + q*8];
            v8s aou = *(const v8s*)&Ou[(w*16+lc)*XTS + kk*32 + q*8];
            v8s bw  = *(const v8s*)&AjH[(ot*16+lc)*XTS + kk*32 + q*8];
            ax = mfma16(aox, bw, ax);
            au = mfma16(aou, bw, au);
        }
        #pragma unroll
        for (int r = 0; r < 4; ++r) {
            int i = i0 + w*16 + q*4 + r;
            int o = ot*16 + lc;
            size_t idx = ((size_t)((b*NN + i)*TT + t))*FF + o;
            out[idx]           = fmaxf(ax[r], 0.0f);
            out[OUT_OFF + idx] = fmaxf(au[r], 0.0f);
        }
    }
}

extern "C" void kernel_launch(void* const* d_in, const int* in_sizes, int n_in,
                              void* d_out, int out_size, void* d_ws, size_t ws_size,
                              hipStream_t stream) {
    const float* ori = (const float*)d_in[0];
    const float* unc = (const float*)d_in[1];
    const float* emb = (const float*)d_in[2];
    const float* W1  = (const float*)d_in[3];
    float* out = (float*)d_out;

    spag_kernel<<<dim3(BB*TT*8), dim3(256), 0, stream>>>(ori, unc, emb, W1, out);
}